// Round 1
// baseline (3633.083 us; speedup 1.0000x reference)
//
#include <hip/hip_runtime.h>
#include <math.h>

constexpr int B_ = 2, C_ = 32, NS = 32, NZ = 96, NX = 96;
constexpr int M1 = 8, M2 = 12, M3 = 12;
constexpr int KS = 16, KZ = 24, KX = 12;          // kept mode counts (s, z, x)
constexpr int NPTS = B_ * NS * NZ * NX;           // 589824
constexpr int CHS  = NS * NZ * NX;                // 294912 (per-channel stride)
constexpr size_t HSIZE = (size_t)B_ * C_ * CHS;   // 18,874,368 floats

constexpr size_t FX_C  = (size_t)B_ * C_ * NS * KX * NZ;  // 2,359,296 cplx
constexpr size_t FZX_C = (size_t)B_ * C_ * KZ * KX * NS;  //   589,824 cplx
constexpr size_t FS_C  = (size_t)B_ * KS * KZ * KX * C_;  //   294,912 cplx

// workspace offsets (floats). GiS overlays FZX, GiZ overlays FX (sizes match).
constexpr size_t OFF_HA   = 0;
constexpr size_t OFF_HB   = OFF_HA + HSIZE;
constexpr size_t OFF_FX   = OFF_HB + HSIZE;
constexpr size_t OFF_FZX  = OFF_FX + 2 * FX_C;
constexpr size_t OFF_FS   = OFF_FZX + 2 * FZX_C;
constexpr size_t OFF_G    = OFF_FS + 2 * FS_C;
constexpr size_t OFF_ST   = OFF_G + 2 * FS_C;     // 64 floats: sum[32], sumsq[32]
constexpr size_t OFF_TWXF = OFF_ST + 64;          // [x=96][k=12] cplx, e^{-i}
constexpr size_t OFF_TWZF = OFF_TWXF + 2 * 96 * 12;
constexpr size_t OFF_TWSF = OFF_TWZF + 2 * 96 * 24;   // includes 1/294912
constexpr size_t OFF_TWSI = OFF_TWSF + 2 * 32 * 16;   // [k=16][s=32] cplx, e^{+i}
constexpr size_t OFF_TWZI = OFF_TWSI + 2 * 16 * 32;   // [k=24][z=96]
constexpr size_t OFF_TWXI = OFF_TWZI + 2 * 24 * 96;   // [k=12][x=96]
// end = OFF_TWXI + 2*12*96  -> 44,842,560 floats ~= 171 MB

__global__ void k_init_tw(float* ws) {
  const double TWO_PI = 6.283185307179586476925286766559;
  int t = threadIdx.x;
  float2* twxf = (float2*)(ws + OFF_TWXF);
  for (int i = t; i < 96 * 12; i += 256) {
    int x = i / 12, k = i % 12;
    double a = -TWO_PI * (double)((k * x) % 96) / 96.0;
    twxf[i] = make_float2((float)cos(a), (float)sin(a));
  }
  float2* twzf = (float2*)(ws + OFF_TWZF);
  for (int i = t; i < 96 * 24; i += 256) {
    int z = i / 24, k = i % 24;
    double a = -TWO_PI * (double)((k * z) % 96) / 96.0;
    twzf[i] = make_float2((float)cos(a), (float)sin(a));
  }
  float2* twsf = (float2*)(ws + OFF_TWSF);
  const double SC = 1.0 / (double)(NS * NZ * NX);  // fftn norm='forward'
  for (int i = t; i < 32 * 16; i += 256) {
    int s = i / 16, k = i % 16;
    int f = (k < 8) ? k : k + 16;                  // s-modes 0..7, 24..31
    double a = -TWO_PI * (double)((f * s) % 32) / 32.0;
    twsf[i] = make_float2((float)(cos(a) * SC), (float)(sin(a) * SC));
  }
  float2* twsi = (float2*)(ws + OFF_TWSI);
  for (int i = t; i < 16 * 32; i += 256) {
    int k = i / 32, s = i % 32;
    int f = (k < 8) ? k : k + 16;
    double a = TWO_PI * (double)((f * s) % 32) / 32.0;
    twsi[i] = make_float2((float)cos(a), (float)sin(a));
  }
  float2* twzi = (float2*)(ws + OFF_TWZI);
  for (int i = t; i < 24 * 96; i += 256) {
    int k = i / 96, z = i % 96;
    int f = (k < 12) ? k : k + 72;                 // z-modes 0..11, 84..95
    double a = TWO_PI * (double)((f * z) % 96) / 96.0;
    twzi[i] = make_float2((float)cos(a), (float)sin(a));
  }
  float2* twxi = (float2*)(ws + OFF_TWXI);
  for (int i = t; i < 12 * 96; i += 256) {
    int k = i / 96, x = i % 96;
    double a = TWO_PI * (double)((k * x) % 96) / 96.0;
    twxi[i] = make_float2((float)cos(a), (float)sin(a));
  }
}

// h[b][c][s][z][x] = x0*w[0][c] + x1*w[1][c] + b[c]
__global__ void k_fc0(const float* __restrict__ xin, const float* __restrict__ w,
                      const float* __restrict__ bias, float* __restrict__ h) {
  int pt = blockIdx.x * 256 + threadIdx.x;
  float x0 = xin[2 * pt], x1 = xin[2 * pt + 1];
  int x = pt % NX, z = (pt / NX) % NZ, s = (pt / (NX * NZ)) % NS, b = pt / (NX * NZ * NS);
  size_t base = (size_t)b * C_ * CHS + (size_t)s * NZ * NX + (size_t)z * NX + x;
  for (int c = 0; c < C_; ++c)
    h[base + (size_t)c * CHS] = x0 * w[c] + x1 * w[C_ + c] + bias[c];
}

// Fx[b][c][s][kx][z] = sum_x h * e^{-2pi i kx x/96}
__global__ void k_dftx(const float* __restrict__ h, float2* __restrict__ fx,
                       const float2* __restrict__ tw) {
  int tid = blockIdx.x * 256 + threadIdx.x;   // 2,359,296
  int kx = tid % KX;
  int r  = tid / KX;                          // (b,c,s,z)
  int z = r % NZ, bcs = r / NZ;
  const float* row = h + (size_t)bcs * NZ * NX + (size_t)z * NX;
  float fr = 0.f, fi = 0.f;
  for (int x = 0; x < NX; ++x) {
    float v = row[x];
    float2 t = tw[x * KX + kx];
    fr += v * t.x; fi += v * t.y;
  }
  fx[((size_t)bcs * KX + kx) * NZ + z] = make_float2(fr, fi);
}

// Fzx[b][c][kz][kx][s] = sum_z Fx * e^{-2pi i kz z/96}
__global__ void k_dftz(const float2* __restrict__ fx, float2* __restrict__ fzx,
                       const float2* __restrict__ tw) {
  int tid = blockIdx.x * 256 + threadIdx.x;   // 589,824
  int kz = tid % KZ;
  int r2 = tid / KZ;                          // (b,c,s,kx)
  const float2* row = fx + (size_t)r2 * NZ;
  float fr = 0.f, fi = 0.f;
  for (int z = 0; z < NZ; ++z) {
    float2 v = row[z];
    float2 t = tw[z * KZ + kz];
    fr += v.x * t.x - v.y * t.y;
    fi += v.x * t.y + v.y * t.x;
  }
  int kx = r2 % KX, s = (r2 / KX) % NS, bc = r2 / (KX * NS);
  fzx[(((size_t)bc * KZ + kz) * KX + kx) * NS + s] = make_float2(fr, fi);
}

// Fs[b][ks][kz][kx][c] = sum_s Fzx * e^{-2pi i f(ks) s/32} / 294912
__global__ void k_dfts(const float2* __restrict__ fzx, float2* __restrict__ fs,
                       const float2* __restrict__ tw) {
  int tid = blockIdx.x * 256 + threadIdx.x;   // 294,912
  int ks = tid % KS;
  int r3 = tid / KS;                          // (b,c,kz,kx)
  const float2* row = fzx + (size_t)r3 * NS;
  float fr = 0.f, fi = 0.f;
  for (int s = 0; s < NS; ++s) {
    float2 v = row[s];
    float2 t = tw[s * KS + ks];
    fr += v.x * t.x - v.y * t.y;
    fi += v.x * t.y + v.y * t.x;
  }
  int kx = r3 % KX, kz = (r3 / KX) % KZ, c = (r3 / (KX * KZ)) % C_, b = r3 / (KX * KZ * C_);
  fs[((((size_t)b * KS + ks) * KZ + kz) * KX + kx) * C_ + c] = make_float2(fr, fi);
}

// G[b][o][kz][kx][ks] = sum_i Fs[b][..][i] * wc[quad][i][o]; both b in one thread
__global__ void k_mix(const float2* __restrict__ fs, const float* __restrict__ spec,
                      int l, float2* __restrict__ g) {
  int tid = blockIdx.x * 256 + threadIdx.x;   // 147,456
  int o  = tid % C_;
  int kx = (tid / C_) % KX;
  int kz = (tid / (C_ * KX)) % KZ;
  int ks = tid / (C_ * KX * KZ);
  int q  = (ks >= M1 ? 1 : 0) + (kz >= M2 ? 2 : 0);
  int m1 = ks & 7, m2 = kz % M2, m3 = kx;
  const float2* F0 = fs + (((size_t)ks * KZ + kz) * KX + kx) * C_;
  const float2* F1 = F0 + (size_t)KS * KZ * KX * C_;          // b=1
  const float* wp = spec + (size_t)(l * 4 + q) * 2359296 + (size_t)o * 2304
                    + m1 * 288 + m2 * 24 + m3 * 2;
  float a0r = 0.f, a0i = 0.f, a1r = 0.f, a1i = 0.f;
  for (int i = 0; i < C_; ++i) {
    float wr = wp[0], wi = wp[1];
    wp += 73728;                                               // i-stride
    float2 f0 = F0[i], f1 = F1[i];
    a0r += f0.x * wr - f0.y * wi;  a0i += f0.x * wi + f0.y * wr;
    a1r += f1.x * wr - f1.y * wi;  a1i += f1.x * wi + f1.y * wr;
  }
  size_t ob = (((size_t)o * KZ + kz) * KX + kx) * KS + ks;
  g[ob] = make_float2(a0r, a0i);
  g[ob + (size_t)C_ * KZ * KX * KS] = make_float2(a1r, a1i);
}

// Gs[b][o][s][kx][kz] = sum_ks G * e^{+2pi i f(ks) s/32}
__global__ void k_idfts(const float2* __restrict__ g, float2* __restrict__ gs,
                        const float2* __restrict__ tw) {
  int tid = blockIdx.x * 256 + threadIdx.x;   // 589,824
  int s  = tid % NS;
  int r4 = tid / NS;                          // (b,o,kz,kx)
  const float2* row = g + (size_t)r4 * KS;
  float fr = 0.f, fi = 0.f;
  for (int k = 0; k < KS; ++k) {
    float2 v = row[k];
    float2 t = tw[k * NS + s];
    fr += v.x * t.x - v.y * t.y;
    fi += v.x * t.y + v.y * t.x;
  }
  int kx = r4 % KX, kz = (r4 / KX) % KZ, o = (r4 / (KX * KZ)) % C_, b = r4 / (KX * KZ * C_);
  gs[((((size_t)b * C_ + o) * NS + s) * KX + kx) * KZ + kz] = make_float2(fr, fi);
}

// Gz[b][o][s][z][kx] = sum_kz Gs * e^{+2pi i f(kz) z/96}
__global__ void k_idftz(const float2* __restrict__ gs, float2* __restrict__ gz,
                        const float2* __restrict__ tw) {
  int tid = blockIdx.x * 256 + threadIdx.x;   // 2,359,296
  int z  = tid % NZ;
  int r5 = tid / NZ;                          // (b,o,s,kx)
  const float2* row = gs + (size_t)r5 * KZ;
  float fr = 0.f, fi = 0.f;
  for (int k = 0; k < KZ; ++k) {
    float2 v = row[k];
    float2 t = tw[k * NZ + z];
    fr += v.x * t.x - v.y * t.y;
    fi += v.x * t.y + v.y * t.x;
  }
  int kx = r5 % KX, s = (r5 / KX) % NS, o = (r5 / (KX * NS)) % C_, b = r5 / (KX * NS * C_);
  gz[((((size_t)b * C_ + o) * NS + s) * NZ + z) * KX + kx] = make_float2(fr, fi);
}

// a[b][o][s][z][x] = Re(sum_kx Gz e^{+2pi i kx x/96}) + sum_i w_w[o][i] h[b][i][s][z][x] + w_b[o]
__global__ void k_idftx_fuse(const float2* __restrict__ gz, const float* __restrict__ hsrc,
                             const float* __restrict__ ww, const float* __restrict__ wb,
                             const float2* __restrict__ twxi, float* __restrict__ adst) {
  __shared__ float  sh_h[C_ * NX];    // 12 KB
  __shared__ float2 sh_g[C_ * KX];    // 3 KB
  int blk = blockIdx.x;               // (b,s,z)
  int z = blk % NZ, s = (blk / NZ) % NS, b = blk / (NZ * NS);
  int t = threadIdx.x;                // 384
  size_t rowbase = ((size_t)b * C_) * CHS + (size_t)s * NZ * NX + (size_t)z * NX;
  for (int i = t; i < C_ * NX; i += 384) {
    int c = i / NX, x = i % NX;
    sh_h[i] = hsrc[rowbase + (size_t)c * CHS + x];
  }
  {
    int o = t / KX, kx = t % KX;
    sh_g[t] = gz[((((size_t)b * C_ + o) * NS + s) * NZ + z) * KX + kx];
  }
  __syncthreads();
  int x = t % NX, og = t / NX;        // og 0..3
  float2 tw[KX];
  #pragma unroll
  for (int k = 0; k < KX; ++k) tw[k] = twxi[k * NX + x];
  for (int j = 0; j < 8; ++j) {
    int o = og * 8 + j;
    float acc = wb[o];
    const float2* gr = sh_g + o * KX;
    #pragma unroll
    for (int k = 0; k < KX; ++k) acc += gr[k].x * tw[k].x - gr[k].y * tw[k].y;
    const float* wrow = ww + o * C_;
    #pragma unroll
    for (int i = 0; i < C_; ++i) acc += wrow[i] * sh_h[i * NX + x];
    adst[rowbase + (size_t)o * CHS + x] = acc;
  }
}

__global__ void k_zero_stats(float* st) {
  if (threadIdx.x < 64) st[threadIdx.x] = 0.f;
}

__global__ void k_bnstats(const float* __restrict__ a, float* __restrict__ st) {
  int bc = blockIdx.x >> 4;           // (b,c) 0..63
  int chunk = blockIdx.x & 15;
  const float* p = a + (size_t)bc * CHS + (size_t)chunk * 18432;
  float s = 0.f, s2 = 0.f;
  for (int i = threadIdx.x; i < 18432; i += 256) {
    float v = p[i];
    s += v; s2 += v * v;
  }
  for (int off = 32; off > 0; off >>= 1) {
    s  += __shfl_down(s, off);
    s2 += __shfl_down(s2, off);
  }
  __shared__ float rs[4], rs2[4];
  if ((threadIdx.x & 63) == 0) { rs[threadIdx.x >> 6] = s; rs2[threadIdx.x >> 6] = s2; }
  __syncthreads();
  if (threadIdx.x == 0) {
    float S = rs[0] + rs[1] + rs[2] + rs[3];
    float S2 = rs2[0] + rs2[1] + rs2[2] + rs2[3];
    int c = bc & 31;
    atomicAdd(&st[c], S);
    atomicAdd(&st[32 + c], S2);
  }
}

__global__ void k_bn_apply(float* __restrict__ a, const float* __restrict__ st,
                           const float* __restrict__ g, const float* __restrict__ bb) {
  size_t idx = (size_t)blockIdx.x * 256 + threadIdx.x;  // HSIZE threads
  int c = (int)((idx / CHS) & 31);
  const float N = (float)NPTS;
  float mean = st[c] / N;
  float var = st[32 + c] / N - mean * mean;
  float inv = rsqrtf(var + 1e-5f);
  float gv = g[c], bv = bb[c];
  float v = (a[idx] - mean) * inv * gv + bv;
  a[idx] = v >= 0.f ? v : 0.1f * v;
}

template <int K, int SIN, int M, int SOUT>
__device__ __forceinline__ void mlp_layer(const float* sin_, float* sout,
                                          const float* __restrict__ w,
                                          const float* __restrict__ bias, int p, int q) {
  constexpr int MQ = M / 4;
  float acc[MQ];
  const int m0 = q * MQ;
  #pragma unroll
  for (int j = 0; j < MQ; ++j) acc[j] = 0.f;
  const float* srow = sin_ + p * SIN;
  for (int k = 0; k < K; ++k) {
    float av = srow[k];
    const float* wr = w + k * M + m0;
    #pragma unroll
    for (int j = 0; j < MQ; ++j) acc[j] += av * wr[j];
  }
  float* orow = sout + p * SOUT;
  #pragma unroll
  for (int j = 0; j < MQ; ++j) {
    float v = acc[j] + bias[m0 + j];
    orow[m0 + j] = v >= 0.f ? v : 0.1f * v;
  }
}

__global__ __launch_bounds__(256) void k_mlp(
    const float* __restrict__ h, const float* __restrict__ xin,
    const float* __restrict__ w1, const float* __restrict__ b1,
    const float* __restrict__ w2, const float* __restrict__ b2,
    const float* __restrict__ w3, const float* __restrict__ b3,
    const float* __restrict__ w4, const float* __restrict__ b4,
    const float* __restrict__ w5, const float* __restrict__ b5,
    const float* __restrict__ w7, const float* __restrict__ b7,
    float* __restrict__ out) {
  __shared__ float A[64 * 65];    // widths <= 64; stride 65 -> (p+k)%32 banks
  __shared__ float Bf[64 * 129];  // widths <= 128
  int t = threadIdx.x;
  int p = t & 63, q = t >> 6;
  int pt = blockIdx.x * 64 + p;
  int x = pt % NX, z = (pt / NX) % NZ, s = (pt / (NX * NZ)) % NS, b = pt / (NX * NZ * NS);
  size_t base = (size_t)b * C_ * CHS + (size_t)s * NZ * NX + (size_t)z * NX + x;
  #pragma unroll
  for (int i = 0; i < 8; ++i) {
    int c = q * 8 + i;
    A[p * 65 + c] = h[base + (size_t)c * CHS];
  }
  __syncthreads();
  mlp_layer<32, 65, 128, 129>(A, Bf, w1, b1, p, q);   __syncthreads();
  mlp_layer<128, 129, 64, 65>(Bf, A, w2, b2, p, q);   __syncthreads();
  mlp_layer<64, 65, 32, 129>(A, Bf, w3, b3, p, q);    __syncthreads();
  mlp_layer<32, 129, 64, 65>(Bf, A, w4, b4, p, q);    __syncthreads();
  mlp_layer<64, 65, 128, 129>(A, Bf, w5, b5, p, q);   __syncthreads();
  if (q == 0) {
    float acc = b7[0];
    const float* srow = Bf + p * 129;
    for (int k = 0; k < 128; ++k) acc += srow[k] * w7[k];
    float T0 = xin[2 * pt + 1];
    float mask = (T0 < 0.01f) ? T0 : 1.0f;
    if (z < 2) mask = 0.f;
    out[pt] = acc * mask;
  }
}

__global__ void k_loss(const float* __restrict__ tau, const float* __restrict__ xin,
                       const float* __restrict__ y, float* __restrict__ loss) {
  int pt = blockIdx.x * 256 + threadIdx.x;
  int x = pt % NX, z = (pt / NX) % NZ;
  float tpx = (x < NX - 1) ? tau[pt + 1] : 0.f;
  float tmx = (x > 0) ? tau[pt - 1] : 0.f;
  float tpz = (z < NZ - 1) ? tau[pt + NX] : 0.f;
  float tmz = (z > 0) ? tau[pt - NX] : 0.f;
  float Tpx = (x < NX - 1) ? xin[2 * (pt + 1) + 1] : 0.f;
  float Tmx = (x > 0) ? xin[2 * (pt - 1) + 1] : 0.f;
  float Tpz = (z < NZ - 1) ? xin[2 * (pt + NX) + 1] : 0.f;
  float Tmz = (z > 0) ? xin[2 * (pt - NX) + 1] : 0.f;
  float dx = (tpx - tmx) * 50.f + (Tpx - Tmx) * 50.f;
  float dz = (tpz - tmz) * 50.f + (Tpz - Tmz) * 50.f;
  loss[pt] = dx * dx + dz * dz - y[pt];
}

extern "C" void kernel_launch(void* const* d_in, const int* in_sizes, int n_in,
                              void* d_out, int out_size, void* d_ws, size_t ws_size,
                              hipStream_t stream) {
  (void)in_sizes; (void)n_in; (void)out_size; (void)ws_size;
  const float* xin    = (const float*)d_in[0];
  const float* y      = (const float*)d_in[1];
  const float* fc0_w  = (const float*)d_in[2];
  const float* fc0_b  = (const float*)d_in[3];
  const float* spec_w = (const float*)d_in[4];
  const float* w_w    = (const float*)d_in[5];
  const float* w_b    = (const float*)d_in[6];
  const float* bn_g   = (const float*)d_in[7];
  const float* bn_b   = (const float*)d_in[8];
  const float* fc1_w  = (const float*)d_in[9];
  const float* fc1_b  = (const float*)d_in[10];
  const float* fc2_w  = (const float*)d_in[11];
  const float* fc2_b  = (const float*)d_in[12];
  const float* fc3_w  = (const float*)d_in[13];
  const float* fc3_b  = (const float*)d_in[14];
  const float* fc4_w  = (const float*)d_in[15];
  const float* fc4_b  = (const float*)d_in[16];
  const float* fc5_w  = (const float*)d_in[17];
  const float* fc5_b  = (const float*)d_in[18];
  const float* fc7_w  = (const float*)d_in[19];
  const float* fc7_b  = (const float*)d_in[20];
  float* ws  = (float*)d_ws;
  float* out = (float*)d_out;

  k_init_tw<<<1, 256, 0, stream>>>(ws);
  k_fc0<<<NPTS / 256, 256, 0, stream>>>(xin, fc0_w, fc0_b, ws + OFF_HA);

  float* hsrc = ws + OFF_HA;
  float* hdst = ws + OFF_HB;
  for (int l = 0; l < 4; ++l) {
    k_dftx<<<(int)(FX_C / 256), 256, 0, stream>>>(hsrc, (float2*)(ws + OFF_FX),
                                                  (const float2*)(ws + OFF_TWXF));
    k_dftz<<<(int)(FZX_C * KZ / KZ / 256 * 1), 256, 0, stream>>>((const float2*)(ws + OFF_FX),
                                                  (float2*)(ws + OFF_FZX),
                                                  (const float2*)(ws + OFF_TWZF));
    k_dfts<<<(int)(FS_C / 256), 256, 0, stream>>>((const float2*)(ws + OFF_FZX),
                                                  (float2*)(ws + OFF_FS),
                                                  (const float2*)(ws + OFF_TWSF));
    k_mix<<<147456 / 256, 256, 0, stream>>>((const float2*)(ws + OFF_FS), spec_w, l,
                                            (float2*)(ws + OFF_G));
    k_idfts<<<(int)(FZX_C / 256), 256, 0, stream>>>((const float2*)(ws + OFF_G),
                                                    (float2*)(ws + OFF_FZX),
                                                    (const float2*)(ws + OFF_TWSI));
    k_idftz<<<(int)(FX_C / 256), 256, 0, stream>>>((const float2*)(ws + OFF_FZX),
                                                   (float2*)(ws + OFF_FX),
                                                   (const float2*)(ws + OFF_TWZI));
    k_idftx_fuse<<<B_ * NS * NZ, 384, 0, stream>>>((const float2*)(ws + OFF_FX), hsrc,
                                                   w_w + (size_t)l * C_ * C_, w_b + (size_t)l * C_,
                                                   (const float2*)(ws + OFF_TWXI), hdst);
    k_zero_stats<<<1, 64, 0, stream>>>(ws + OFF_ST);
    k_bnstats<<<1024, 256, 0, stream>>>(hdst, ws + OFF_ST);
    k_bn_apply<<<(int)(HSIZE / 256), 256, 0, stream>>>(hdst, ws + OFF_ST,
                                                       bn_g + (size_t)l * C_, bn_b + (size_t)l * C_);
    float* tmp = hsrc; hsrc = hdst; hdst = tmp;
  }

  k_mlp<<<NPTS / 64, 256, 0, stream>>>(hsrc, xin, fc1_w, fc1_b, fc2_w, fc2_b, fc3_w, fc3_b,
                                       fc4_w, fc4_b, fc5_w, fc5_b, fc7_w, fc7_b, out);
  k_loss<<<NPTS / 256, 256, 0, stream>>>(out, xin, y, out + NPTS);
}

// Round 2
// 2454.757 us; speedup vs baseline: 1.4800x; 1.4800x over previous
//
#include <hip/hip_runtime.h>
#include <math.h>

constexpr int B_ = 2, C_ = 32, NS = 32, NZ = 96, NX = 96;
constexpr int M1 = 8, M2 = 12, M3 = 12;
constexpr int KS = 16, KZ = 24, KX = 12;          // kept mode counts (s, z, x)
constexpr int NPTS = B_ * NS * NZ * NX;           // 589824
constexpr int CHS  = NS * NZ * NX;                // 294912 (per-channel stride)
constexpr size_t HSIZE = (size_t)B_ * C_ * CHS;   // 18,874,368 floats

constexpr size_t FX_C  = (size_t)B_ * C_ * NS * KX * NZ;  // 2,359,296 cplx
constexpr size_t FZX_C = (size_t)B_ * C_ * KZ * KX * NS;  //   589,824 cplx
constexpr size_t FS_C  = (size_t)B_ * KS * KZ * KX * C_;  //   294,912 cplx

// workspace offsets (floats). GiS overlays FZX, GiZ overlays FX (sizes match).
constexpr size_t OFF_HA   = 0;
constexpr size_t OFF_HB   = OFF_HA + HSIZE;
constexpr size_t OFF_FX   = OFF_HB + HSIZE;
constexpr size_t OFF_FZX  = OFF_FX + 2 * FX_C;
constexpr size_t OFF_FS   = OFF_FZX + 2 * FZX_C;
constexpr size_t OFF_G    = OFF_FS + 2 * FS_C;
constexpr size_t OFF_ST   = OFF_G + 2 * FS_C;     // 64 floats: sum[32], sumsq[32]
constexpr size_t OFF_TWXF = OFF_ST + 64;          // [x=96][k=12] cplx, e^{-i}
constexpr size_t OFF_TWZF = OFF_TWXF + 2 * 96 * 12;
constexpr size_t OFF_TWSF = OFF_TWZF + 2 * 96 * 24;   // includes 1/294912
constexpr size_t OFF_TWSI = OFF_TWSF + 2 * 32 * 16;   // [k=16][s=32] cplx, e^{+i}
constexpr size_t OFF_TWZI = OFF_TWSI + 2 * 16 * 32;   // [k=24][z=96]
constexpr size_t OFF_TWXI = OFF_TWZI + 2 * 24 * 96;   // [k=12][x=96]

__global__ void k_init_tw(float* ws) {
  const double TWO_PI = 6.283185307179586476925286766559;
  int t = threadIdx.x;
  float2* twxf = (float2*)(ws + OFF_TWXF);
  for (int i = t; i < 96 * 12; i += 256) {
    int x = i / 12, k = i % 12;
    double a = -TWO_PI * (double)((k * x) % 96) / 96.0;
    twxf[i] = make_float2((float)cos(a), (float)sin(a));
  }
  float2* twzf = (float2*)(ws + OFF_TWZF);
  for (int i = t; i < 96 * 24; i += 256) {
    int z = i / 24, k = i % 24;
    double a = -TWO_PI * (double)((k * z) % 96) / 96.0;
    twzf[i] = make_float2((float)cos(a), (float)sin(a));
  }
  float2* twsf = (float2*)(ws + OFF_TWSF);
  const double SC = 1.0 / (double)(NS * NZ * NX);  // fftn norm='forward'
  for (int i = t; i < 32 * 16; i += 256) {
    int s = i / 16, k = i % 16;
    int f = (k < 8) ? k : k + 16;                  // s-modes 0..7, 24..31
    double a = -TWO_PI * (double)((f * s) % 32) / 32.0;
    twsf[i] = make_float2((float)(cos(a) * SC), (float)(sin(a) * SC));
  }
  float2* twsi = (float2*)(ws + OFF_TWSI);
  for (int i = t; i < 16 * 32; i += 256) {
    int k = i / 32, s = i % 32;
    int f = (k < 8) ? k : k + 16;
    double a = TWO_PI * (double)((f * s) % 32) / 32.0;
    twsi[i] = make_float2((float)cos(a), (float)sin(a));
  }
  float2* twzi = (float2*)(ws + OFF_TWZI);
  for (int i = t; i < 24 * 96; i += 256) {
    int k = i / 96, z = i % 96;
    int f = (k < 12) ? k : k + 72;                 // z-modes 0..11, 84..95
    double a = TWO_PI * (double)((f * z) % 96) / 96.0;
    twzi[i] = make_float2((float)cos(a), (float)sin(a));
  }
  float2* twxi = (float2*)(ws + OFF_TWXI);
  for (int i = t; i < 12 * 96; i += 256) {
    int k = i / 96, x = i % 96;
    double a = TWO_PI * (double)((k * x) % 96) / 96.0;
    twxi[i] = make_float2((float)cos(a), (float)sin(a));
  }
}

// h[b][c][s][z][x] = x0*w[0][c] + x1*w[1][c] + b[c]
__global__ void k_fc0(const float* __restrict__ xin, const float* __restrict__ w,
                      const float* __restrict__ bias, float* __restrict__ h) {
  int pt = blockIdx.x * 256 + threadIdx.x;
  float x0 = xin[2 * pt], x1 = xin[2 * pt + 1];
  int x = pt % NX, z = (pt / NX) % NZ, s = (pt / (NX * NZ)) % NS, b = pt / (NX * NZ * NS);
  size_t base = (size_t)b * C_ * CHS + (size_t)s * NZ * NX + (size_t)z * NX + x;
  for (int c = 0; c < C_; ++c)
    h[base + (size_t)c * CHS] = x0 * w[c] + x1 * w[C_ + c] + bias[c];
}

// Fx[b][c][s][kx][z] = sum_x h * e^{-2pi i kx x/96}
__global__ void k_dftx(const float* __restrict__ h, float2* __restrict__ fx,
                       const float2* __restrict__ tw) {
  int tid = blockIdx.x * 256 + threadIdx.x;   // 2,359,296
  int kx = tid % KX;
  int r  = tid / KX;                          // (b,c,s,z)
  int z = r % NZ, bcs = r / NZ;
  const float* row = h + (size_t)bcs * NZ * NX + (size_t)z * NX;
  float fr = 0.f, fi = 0.f;
  for (int x = 0; x < NX; ++x) {
    float v = row[x];
    float2 t = tw[x * KX + kx];
    fr += v * t.x; fi += v * t.y;
  }
  fx[((size_t)bcs * KX + kx) * NZ + z] = make_float2(fr, fi);
}

// Fzx[b][c][kz][kx][s] = sum_z Fx * e^{-2pi i kz z/96}
__global__ void k_dftz(const float2* __restrict__ fx, float2* __restrict__ fzx,
                       const float2* __restrict__ tw) {
  int tid = blockIdx.x * 256 + threadIdx.x;   // 589,824
  int kz = tid % KZ;
  int r2 = tid / KZ;                          // (b,c,s,kx)
  const float2* row = fx + (size_t)r2 * NZ;
  float fr = 0.f, fi = 0.f;
  for (int z = 0; z < NZ; ++z) {
    float2 v = row[z];
    float2 t = tw[z * KZ + kz];
    fr += v.x * t.x - v.y * t.y;
    fi += v.x * t.y + v.y * t.x;
  }
  int kx = r2 % KX, s = (r2 / KX) % NS, bc = r2 / (KX * NS);
  fzx[(((size_t)bc * KZ + kz) * KX + kx) * NS + s] = make_float2(fr, fi);
}

// Fs[b][ks][kz][kx][c] = sum_s Fzx * e^{-2pi i f(ks) s/32} / 294912
__global__ void k_dfts(const float2* __restrict__ fzx, float2* __restrict__ fs,
                       const float2* __restrict__ tw) {
  int tid = blockIdx.x * 256 + threadIdx.x;   // 294,912
  int ks = tid % KS;
  int r3 = tid / KS;                          // (b,c,kz,kx)
  const float2* row = fzx + (size_t)r3 * NS;
  float fr = 0.f, fi = 0.f;
  for (int s = 0; s < NS; ++s) {
    float2 v = row[s];
    float2 t = tw[s * KS + ks];
    fr += v.x * t.x - v.y * t.y;
    fi += v.x * t.y + v.y * t.x;
  }
  int kx = r3 % KX, kz = (r3 / KX) % KZ, c = (r3 / (KX * KZ)) % C_, b = r3 / (KX * KZ * C_);
  fs[((((size_t)b * KS + ks) * KZ + kz) * KX + kx) * C_ + c] = make_float2(fr, fi);
}

// G[b][o][kz][kx][ks] = sum_i Fs[b][..][i] * wc[quad][i][o]; both b in one thread
__global__ void k_mix(const float2* __restrict__ fs, const float* __restrict__ spec,
                      int l, float2* __restrict__ g) {
  int tid = blockIdx.x * 256 + threadIdx.x;   // 147,456
  int o  = tid % C_;
  int kx = (tid / C_) % KX;
  int kz = (tid / (C_ * KX)) % KZ;
  int ks = tid / (C_ * KX * KZ);
  int q  = (ks >= M1 ? 1 : 0) + (kz >= M2 ? 2 : 0);
  int m1 = ks & 7, m2 = kz % M2, m3 = kx;
  const float2* F0 = fs + (((size_t)ks * KZ + kz) * KX + kx) * C_;
  const float2* F1 = F0 + (size_t)KS * KZ * KX * C_;          // b=1
  const float* wp = spec + (size_t)(l * 4 + q) * 2359296 + (size_t)o * 2304
                    + m1 * 288 + m2 * 24 + m3 * 2;
  float a0r = 0.f, a0i = 0.f, a1r = 0.f, a1i = 0.f;
  for (int i = 0; i < C_; ++i) {
    float wr = wp[0], wi = wp[1];
    wp += 73728;                                               // i-stride
    float2 f0 = F0[i], f1 = F1[i];
    a0r += f0.x * wr - f0.y * wi;  a0i += f0.x * wi + f0.y * wr;
    a1r += f1.x * wr - f1.y * wi;  a1i += f1.x * wi + f1.y * wr;
  }
  size_t ob = (((size_t)o * KZ + kz) * KX + kx) * KS + ks;
  g[ob] = make_float2(a0r, a0i);
  g[ob + (size_t)C_ * KZ * KX * KS] = make_float2(a1r, a1i);
}

// Gs[b][o][s][kx][kz] = sum_ks G * e^{+2pi i f(ks) s/32}
__global__ void k_idfts(const float2* __restrict__ g, float2* __restrict__ gs,
                        const float2* __restrict__ tw) {
  int tid = blockIdx.x * 256 + threadIdx.x;   // 589,824
  int s  = tid % NS;
  int r4 = tid / NS;                          // (b,o,kz,kx)
  const float2* row = g + (size_t)r4 * KS;
  float fr = 0.f, fi = 0.f;
  for (int k = 0; k < KS; ++k) {
    float2 v = row[k];
    float2 t = tw[k * NS + s];
    fr += v.x * t.x - v.y * t.y;
    fi += v.x * t.y + v.y * t.x;
  }
  int kx = r4 % KX, kz = (r4 / KX) % KZ, o = (r4 / (KX * KZ)) % C_, b = r4 / (KX * KZ * C_);
  gs[((((size_t)b * C_ + o) * NS + s) * KX + kx) * KZ + kz] = make_float2(fr, fi);
}

// Gz[b][o][s][z][kx] = sum_kz Gs * e^{+2pi i f(kz) z/96}
__global__ void k_idftz(const float2* __restrict__ gs, float2* __restrict__ gz,
                        const float2* __restrict__ tw) {
  int tid = blockIdx.x * 256 + threadIdx.x;   // 2,359,296
  int z  = tid % NZ;
  int r5 = tid / NZ;                          // (b,o,s,kx)
  const float2* row = gs + (size_t)r5 * KZ;
  float fr = 0.f, fi = 0.f;
  for (int k = 0; k < KZ; ++k) {
    float2 v = row[k];
    float2 t = tw[k * NZ + z];
    fr += v.x * t.x - v.y * t.y;
    fi += v.x * t.y + v.y * t.x;
  }
  int kx = r5 % KX, s = (r5 / KX) % NS, o = (r5 / (KX * NS)) % C_, b = r5 / (KX * NS * C_);
  gz[((((size_t)b * C_ + o) * NS + s) * NZ + z) * KX + kx] = make_float2(fr, fi);
}

// a[b][o][s][z][x] = Re(sum_kx Gz e^{+2pi i kx x/96}) + sum_i w_w[o][i] h[b][i][s][z][x] + w_b[o]
__global__ void k_idftx_fuse(const float2* __restrict__ gz, const float* __restrict__ hsrc,
                             const float* __restrict__ ww, const float* __restrict__ wb,
                             const float2* __restrict__ twxi, float* __restrict__ adst) {
  __shared__ float  sh_h[C_ * NX];    // 12 KB
  __shared__ float2 sh_g[C_ * KX];    // 3 KB
  int blk = blockIdx.x;               // (b,s,z)
  int z = blk % NZ, s = (blk / NZ) % NS, b = blk / (NZ * NS);
  int t = threadIdx.x;                // 384
  size_t rowbase = ((size_t)b * C_) * CHS + (size_t)s * NZ * NX + (size_t)z * NX;
  for (int i = t; i < C_ * NX; i += 384) {
    int c = i / NX, x = i % NX;
    sh_h[i] = hsrc[rowbase + (size_t)c * CHS + x];
  }
  {
    int o = t / KX, kx = t % KX;
    sh_g[t] = gz[((((size_t)b * C_ + o) * NS + s) * NZ + z) * KX + kx];
  }
  __syncthreads();
  int x = t % NX, og = t / NX;        // og 0..3
  float2 tw[KX];
  #pragma unroll
  for (int k = 0; k < KX; ++k) tw[k] = twxi[k * NX + x];
  for (int j = 0; j < 8; ++j) {
    int o = og * 8 + j;
    float acc = wb[o];
    const float2* gr = sh_g + o * KX;
    #pragma unroll
    for (int k = 0; k < KX; ++k) acc += gr[k].x * tw[k].x - gr[k].y * tw[k].y;
    const float* wrow = ww + o * C_;
    #pragma unroll
    for (int i = 0; i < C_; ++i) acc += wrow[i] * sh_h[i * NX + x];
    adst[rowbase + (size_t)o * CHS + x] = acc;
  }
}

__global__ void k_zero_stats(float* st) {
  if (threadIdx.x < 64) st[threadIdx.x] = 0.f;
}

__global__ void k_bnstats(const float* __restrict__ a, float* __restrict__ st) {
  int bc = blockIdx.x >> 4;           // (b,c) 0..63
  int chunk = blockIdx.x & 15;
  const float* p = a + (size_t)bc * CHS + (size_t)chunk * 18432;
  float s = 0.f, s2 = 0.f;
  for (int i = threadIdx.x; i < 18432; i += 256) {
    float v = p[i];
    s += v; s2 += v * v;
  }
  for (int off = 32; off > 0; off >>= 1) {
    s  += __shfl_down(s, off);
    s2 += __shfl_down(s2, off);
  }
  __shared__ float rs[4], rs2[4];
  if ((threadIdx.x & 63) == 0) { rs[threadIdx.x >> 6] = s; rs2[threadIdx.x >> 6] = s2; }
  __syncthreads();
  if (threadIdx.x == 0) {
    float S = rs[0] + rs[1] + rs[2] + rs[3];
    float S2 = rs2[0] + rs2[1] + rs2[2] + rs2[3];
    int c = bc & 31;
    atomicAdd(&st[c], S);
    atomicAdd(&st[32 + c], S2);
  }
}

__global__ void k_bn_apply(float* __restrict__ a, const float* __restrict__ st,
                           const float* __restrict__ g, const float* __restrict__ bb) {
  size_t idx = (size_t)blockIdx.x * 256 + threadIdx.x;  // HSIZE threads
  int c = (int)((idx / CHS) & 31);
  const float N = (float)NPTS;
  float mean = st[c] / N;
  float var = st[32 + c] / N - mean * mean;
  float inv = rsqrtf(var + 1e-5f);
  float gv = g[c], bv = bb[c];
  float v = (a[idx] - mean) * inv * gv + bv;
  a[idx] = v >= 0.f ? v : 0.1f * v;
}

// q is WAVE-UNIFORM (passed through readfirstlane) -> weight addresses are
// scalar -> compiler emits s_load (off the VALU/VMEM critical path).
template <int K, int SIN, int M, int SOUT>
__device__ __forceinline__ void mlp_layer(const float* sin_, float* sout,
                                          const float* __restrict__ w,
                                          const float* __restrict__ bias, int p, int q) {
  constexpr int MQ = M / 4;
  float acc[MQ];
  const int m0 = q * MQ;
  #pragma unroll
  for (int j = 0; j < MQ; ++j) acc[j] = 0.f;
  const float* srow = sin_ + p * SIN;
  #pragma unroll 4
  for (int k = 0; k < K; ++k) {
    float av = srow[k];
    const float* wr = w + k * M + m0;
    #pragma unroll
    for (int j = 0; j < MQ; ++j) acc[j] += av * wr[j];
  }
  float* orow = sout + p * SOUT;
  #pragma unroll
  for (int j = 0; j < MQ; ++j) {
    float v = acc[j] + bias[m0 + j];
    orow[m0 + j] = v >= 0.f ? v : 0.1f * v;
  }
}

__global__ __launch_bounds__(256) void k_mlp(
    const float* __restrict__ h, const float* __restrict__ xin,
    const float* __restrict__ w1, const float* __restrict__ b1,
    const float* __restrict__ w2, const float* __restrict__ b2,
    const float* __restrict__ w3, const float* __restrict__ b3,
    const float* __restrict__ w4, const float* __restrict__ b4,
    const float* __restrict__ w5, const float* __restrict__ b5,
    const float* __restrict__ w7, const float* __restrict__ b7,
    float* __restrict__ out) {
  __shared__ float A[64 * 65];    // widths <= 64; stride 65 -> (p+k)%32 banks
  __shared__ float Bf[64 * 129];  // widths <= 128
  int t = threadIdx.x;
  int p = t & 63;
  // q is uniform across each wave (waves are 64 contiguous threads); make it
  // PROVABLY uniform so weight loads go to the scalar path (s_load).
  int q = __builtin_amdgcn_readfirstlane(t >> 6);
  int pt = blockIdx.x * 64 + p;
  int x = pt % NX, z = (pt / NX) % NZ, s = (pt / (NX * NZ)) % NS, b = pt / (NX * NZ * NS);
  size_t base = (size_t)b * C_ * CHS + (size_t)s * NZ * NX + (size_t)z * NX + x;
  #pragma unroll
  for (int i = 0; i < 8; ++i) {
    int c = q * 8 + i;
    A[p * 65 + c] = h[base + (size_t)c * CHS];
  }
  __syncthreads();
  mlp_layer<32, 65, 128, 129>(A, Bf, w1, b1, p, q);   __syncthreads();
  mlp_layer<128, 129, 64, 65>(Bf, A, w2, b2, p, q);   __syncthreads();
  mlp_layer<64, 65, 32, 129>(A, Bf, w3, b3, p, q);    __syncthreads();
  mlp_layer<32, 129, 64, 65>(Bf, A, w4, b4, p, q);    __syncthreads();
  mlp_layer<64, 65, 128, 129>(A, Bf, w5, b5, p, q);   __syncthreads();
  if (q == 0) {
    float acc = b7[0];
    const float* srow = Bf + p * 129;
    #pragma unroll 4
    for (int k = 0; k < 128; ++k) acc += srow[k] * w7[k];
    float T0 = xin[2 * pt + 1];
    float mask = (T0 < 0.01f) ? T0 : 1.0f;
    if (z < 2) mask = 0.f;
    out[pt] = acc * mask;
  }
}

__global__ void k_loss(const float* __restrict__ tau, const float* __restrict__ xin,
                       const float* __restrict__ y, float* __restrict__ loss) {
  int pt = blockIdx.x * 256 + threadIdx.x;
  int x = pt % NX, z = (pt / NX) % NZ;
  float tpx = (x < NX - 1) ? tau[pt + 1] : 0.f;
  float tmx = (x > 0) ? tau[pt - 1] : 0.f;
  float tpz = (z < NZ - 1) ? tau[pt + NX] : 0.f;
  float tmz = (z > 0) ? tau[pt - NX] : 0.f;
  float Tpx = (x < NX - 1) ? xin[2 * (pt + 1) + 1] : 0.f;
  float Tmx = (x > 0) ? xin[2 * (pt - 1) + 1] : 0.f;
  float Tpz = (z < NZ - 1) ? xin[2 * (pt + NX) + 1] : 0.f;
  float Tmz = (z > 0) ? xin[2 * (pt - NX) + 1] : 0.f;
  float dx = (tpx - tmx) * 50.f + (Tpx - Tmx) * 50.f;
  float dz = (tpz - tmz) * 50.f + (Tpz - Tmz) * 50.f;
  loss[pt] = dx * dx + dz * dz - y[pt];
}

extern "C" void kernel_launch(void* const* d_in, const int* in_sizes, int n_in,
                              void* d_out, int out_size, void* d_ws, size_t ws_size,
                              hipStream_t stream) {
  (void)in_sizes; (void)n_in; (void)out_size; (void)ws_size;
  const float* xin    = (const float*)d_in[0];
  const float* y      = (const float*)d_in[1];
  const float* fc0_w  = (const float*)d_in[2];
  const float* fc0_b  = (const float*)d_in[3];
  const float* spec_w = (const float*)d_in[4];
  const float* w_w    = (const float*)d_in[5];
  const float* w_b    = (const float*)d_in[6];
  const float* bn_g   = (const float*)d_in[7];
  const float* bn_b   = (const float*)d_in[8];
  const float* fc1_w  = (const float*)d_in[9];
  const float* fc1_b  = (const float*)d_in[10];
  const float* fc2_w  = (const float*)d_in[11];
  const float* fc2_b  = (const float*)d_in[12];
  const float* fc3_w  = (const float*)d_in[13];
  const float* fc3_b  = (const float*)d_in[14];
  const float* fc4_w  = (const float*)d_in[15];
  const float* fc4_b  = (const float*)d_in[16];
  const float* fc5_w  = (const float*)d_in[17];
  const float* fc5_b  = (const float*)d_in[18];
  const float* fc7_w  = (const float*)d_in[19];
  const float* fc7_b  = (const float*)d_in[20];
  float* ws  = (float*)d_ws;
  float* out = (float*)d_out;

  k_init_tw<<<1, 256, 0, stream>>>(ws);
  k_fc0<<<NPTS / 256, 256, 0, stream>>>(xin, fc0_w, fc0_b, ws + OFF_HA);

  float* hsrc = ws + OFF_HA;
  float* hdst = ws + OFF_HB;
  for (int l = 0; l < 4; ++l) {
    k_dftx<<<(int)(FX_C / 256), 256, 0, stream>>>(hsrc, (float2*)(ws + OFF_FX),
                                                  (const float2*)(ws + OFF_TWXF));
    k_dftz<<<(int)(FZX_C / 256), 256, 0, stream>>>((const float2*)(ws + OFF_FX),
                                                  (float2*)(ws + OFF_FZX),
                                                  (const float2*)(ws + OFF_TWZF));
    k_dfts<<<(int)(FS_C / 256), 256, 0, stream>>>((const float2*)(ws + OFF_FZX),
                                                  (float2*)(ws + OFF_FS),
                                                  (const float2*)(ws + OFF_TWSF));
    k_mix<<<147456 / 256, 256, 0, stream>>>((const float2*)(ws + OFF_FS), spec_w, l,
                                            (float2*)(ws + OFF_G));
    k_idfts<<<(int)(FZX_C / 256), 256, 0, stream>>>((const float2*)(ws + OFF_G),
                                                    (float2*)(ws + OFF_FZX),
                                                    (const float2*)(ws + OFF_TWSI));
    k_idftz<<<(int)(FX_C / 256), 256, 0, stream>>>((const float2*)(ws + OFF_FZX),
                                                   (float2*)(ws + OFF_FX),
                                                   (const float2*)(ws + OFF_TWZI));
    k_idftx_fuse<<<B_ * NS * NZ, 384, 0, stream>>>((const float2*)(ws + OFF_FX), hsrc,
                                                   w_w + (size_t)l * C_ * C_, w_b + (size_t)l * C_,
                                                   (const float2*)(ws + OFF_TWXI), hdst);
    k_zero_stats<<<1, 64, 0, stream>>>(ws + OFF_ST);
    k_bnstats<<<1024, 256, 0, stream>>>(hdst, ws + OFF_ST);
    k_bn_apply<<<(int)(HSIZE / 256), 256, 0, stream>>>(hdst, ws + OFF_ST,
                                                       bn_g + (size_t)l * C_, bn_b + (size_t)l * C_);
    float* tmp = hsrc; hsrc = hdst; hdst = tmp;
  }

  k_mlp<<<NPTS / 64, 256, 0, stream>>>(hsrc, xin, fc1_w, fc1_b, fc2_w, fc2_b, fc3_w, fc3_b,
                                       fc4_w, fc4_b, fc5_w, fc5_b, fc7_w, fc7_b, out);
  k_loss<<<NPTS / 256, 256, 0, stream>>>(out, xin, y, out + NPTS);
}